// Round 7
// baseline (49.151 us; speedup 1.0000x reference)
//
#include <hip/hip_runtime.h>
#include <hip/hip_fp16.h>

// Problem constants (from setup_inputs): L=8, H=32, M=8192, R=16, D=128, S=4096
constexpr int H = 32;
constexpr int S = 4096;
constexpr int D = 128;
constexpr float EPSF = 1e-12f;

typedef float vfloat4 __attribute__((ext_vector_type(4)));

// Fused single kernel (round-4 structure, unroll 4, streaming stores).
// out[side,h,s,d] = f32(f16(||row(side,h,s)||)) * f32(f16(row(side,h,S-1,d)/(||row(side,h,S-1)||+eps)))
//
// Wave w owns rows [w*32, w*32+32); all 32 share one (side, head) since
// 32 | S. Each 32-lane half-wave computes the head's f16-rounded normalized
// last row once into registers, then streams 16 rows: contiguous 16 KB read
// + 16 KB write per wave.
//
// Stores use inline-asm `nt sc0 sc1` (system-scope non-temporal) to attempt
// full cache bypass so the 134 MB read-only input set stays LLC-resident.
// Roofline: 268 MB logical / 6.29 TB/s = 42.6 us if stores still allocate;
// ~30 us if the input becomes fully LLC-resident.
__global__ void VLKV_fused_kernel(const float* __restrict__ K,
                                  const float* __restrict__ V,
                                  float* __restrict__ out) {
    const int tid  = threadIdx.x;
    const int lane = tid & 63;
    const int wv   = tid >> 6;            // wave index in block
    const int half = lane >> 5;           // which row of each pair
    const int li   = lane & 31;           // lane within the 32-lane row group

    const long w     = (long)blockIdx.x * (blockDim.x >> 6) + wv;
    const long row0  = w * 32;                      // first global row of this wave
    const int  side  = (int)(row0 >> 17);           // H*S = 2^17
    const long srow0 = row0 & (long)(H * S - 1);    // row within side
    const int  h     = (int)(srow0 >> 12);          // head (S = 2^12)

    const float* base = (side == 0 ? K : V);

    // ---- startup: f16-rounded normalized last row of this head, in registers ----
    const float4 lv = *(const float4*)(base + ((long)h * S + (S - 1)) * D + li * 4);
    float lss = lv.x * lv.x + lv.y * lv.y + lv.z * lv.z + lv.w * lv.w;
#pragma unroll
    for (int m = 1; m < 32; m <<= 1) lss += __shfl_xor(lss, m);   // within 32-lane half
    const float inv = 1.0f / (sqrtf(lss) + EPSF);
    float4 ln;
    ln.x = __half2float(__float2half(lv.x * inv));
    ln.y = __half2float(__float2half(lv.y * inv));
    ln.z = __half2float(__float2half(lv.z * inv));
    ln.w = __half2float(__float2half(lv.w * inv));

    // ---- main loop: 16 row-pairs, contiguous streams ----
    const float* src = base + (srow0 + half) * (long)D + li * 4;
    float*       dst = out  + (row0  + half) * (long)D + li * 4;

#pragma unroll 4
    for (int i = 0; i < 16; ++i) {
        const float4 x = *(const float4*)(src + (long)i * 2 * D);
        float ss = x.x * x.x + x.y * x.y + x.z * x.z + x.w * x.w;
#pragma unroll
        for (int m = 1; m < 32; m <<= 1) ss += __shfl_xor(ss, m);
        const float nh = __half2float(__float2half(sqrtf(ss)));

        vfloat4 o;
        o.x = nh * ln.x;
        o.y = nh * ln.y;
        o.z = nh * ln.z;
        o.w = nh * ln.w;

        // Streaming store: non-temporal + system scope -> no L2/MALL allocation.
        asm volatile("global_store_dwordx4 %0, %1, off nt sc0 sc1"
                     :
                     : "v"(dst + (long)i * 2 * D), "v"(o)
                     : "memory");
    }
}

extern "C" void kernel_launch(void* const* d_in, const int* in_sizes, int n_in,
                              void* d_out, int out_size, void* d_ws, size_t ws_size,
                              hipStream_t stream) {
    const float* K = (const float*)d_in[0];   // key_states   [1,H,S,D] f32
    const float* V = (const float*)d_in[1];   // value_states [1,H,S,D] f32
    float* out = (float*)d_out;               // [2][H][S][D] f32 (k_full ++ v_full)

    // 8192 waves x 32 rows/wave = 262144 rows = 2*H*S, exact cover.
    VLKV_fused_kernel<<<2048, 256, 0, stream>>>(K, V, out);
}

// Round 9
// 45.072 us; speedup vs baseline: 1.0905x; 1.0905x over previous
//
#include <hip/hip_runtime.h>
#include <hip/hip_fp16.h>

// Problem constants (from setup_inputs): L=8, H=32, M=8192, R=16, D=128, S=4096
constexpr int H = 32;
constexpr int S = 4096;
constexpr int D = 128;
constexpr float EPSF = 1e-12f;

// Fused single kernel (round-4 structure, unroll 4, PLAIN stores).
// out[side,h,s,d] = f32(f16(||row(side,h,s)||)) * f32(f16(row(side,h,S-1,d)/(||row(side,h,S-1)||+eps)))
//
// Wave w owns rows [w*32, w*32+32) of the 2*H*S = 262144 global rows; all 32
// share one (side, head) since 32 | S=4096. Each 32-lane half-wave computes
// the head's f16-rounded normalized last row once into registers, then
// streams 16 rows: contiguous 16 KB read + 16 KB write per wave.
//
// Roofline: 268 MB logical traffic / 6.29 TB/s copy ceiling = 42.6 us floor;
// measured 44.8 us (95%). Experiments that did NOT help:
//  - unroll 8 (R6, +0.4 us): enough loads already in flight at unroll 4
//  - read-pass + write-pass split (R5, +5.8 us): loses read/write concurrency
//  - nt builtin (R3) / asm `nt sc0 sc1` (R7, +4.4 us): FETCH_SIZE pinned at
//    65.7 MB regardless — LLC input residency is capacity-set, not policy-set
//  - nontemporal store REMOVED (R8): perf-neutral everywhere, and implicated
//    in a post-timing visibility divergence under graph replay (absmax 3.875
//    after replays with identical code that validated pre-timing).
__global__ void VLKV_fused_kernel(const float* __restrict__ K,
                                  const float* __restrict__ V,
                                  float* __restrict__ out) {
    const int tid  = threadIdx.x;
    const int lane = tid & 63;
    const int wv   = tid >> 6;            // wave index in block
    const int half = lane >> 5;           // which row of each pair
    const int li   = lane & 31;           // lane within the 32-lane row group

    const long w     = (long)blockIdx.x * (blockDim.x >> 6) + wv;
    const long row0  = w * 32;                      // first global row of this wave
    const int  side  = (int)(row0 >> 17);           // H*S = 2^17
    const long srow0 = row0 & (long)(H * S - 1);    // row within side
    const int  h     = (int)(srow0 >> 12);          // head (S = 2^12)

    const float* base = (side == 0 ? K : V);

    // ---- startup: f16-rounded normalized last row of this head, in registers ----
    const float4 lv = *(const float4*)(base + ((long)h * S + (S - 1)) * D + li * 4);
    float lss = lv.x * lv.x + lv.y * lv.y + lv.z * lv.z + lv.w * lv.w;
#pragma unroll
    for (int m = 1; m < 32; m <<= 1) lss += __shfl_xor(lss, m);   // within 32-lane half
    const float inv = 1.0f / (sqrtf(lss) + EPSF);
    float4 ln;
    ln.x = __half2float(__float2half(lv.x * inv));
    ln.y = __half2float(__float2half(lv.y * inv));
    ln.z = __half2float(__float2half(lv.z * inv));
    ln.w = __half2float(__float2half(lv.w * inv));

    // ---- main loop: 16 row-pairs, contiguous streams ----
    const float* src = base + (srow0 + half) * (long)D + li * 4;
    float*       dst = out  + (row0  + half) * (long)D + li * 4;

#pragma unroll 4
    for (int i = 0; i < 16; ++i) {
        const float4 x = *(const float4*)(src + (long)i * 2 * D);
        float ss = x.x * x.x + x.y * x.y + x.z * x.z + x.w * x.w;
#pragma unroll
        for (int m = 1; m < 32; m <<= 1) ss += __shfl_xor(ss, m);
        const float nh = __half2float(__float2half(sqrtf(ss)));

        float4 o;
        o.x = nh * ln.x;
        o.y = nh * ln.y;
        o.z = nh * ln.z;
        o.w = nh * ln.w;
        *(float4*)(dst + (long)i * 2 * D) = o;
    }
}

extern "C" void kernel_launch(void* const* d_in, const int* in_sizes, int n_in,
                              void* d_out, int out_size, void* d_ws, size_t ws_size,
                              hipStream_t stream) {
    const float* K = (const float*)d_in[0];   // key_states   [1,H,S,D] f32
    const float* V = (const float*)d_in[1];   // value_states [1,H,S,D] f32
    float* out = (float*)d_out;               // [2][H][S][D] f32 (k_full ++ v_full)

    // 8192 waves x 32 rows/wave = 262144 rows = 2*H*S, exact cover.
    VLKV_fused_kernel<<<2048, 256, 0, stream>>>(K, V, out);
}